// Round 6
// baseline (113.501 us; speedup 1.0000x reference)
//
#include <hip/hip_runtime.h>
#include <float.h>

// Chamfer distance, fp32, N=M=16384.
// d(q,t) = |q|^2 + (|t|^2 - 2 q.t). Targets transformed in-kernel to SoA LDS
// (TX=-2x, TY=-2y, TZ=-2z, TW=|t|^2). Queries are wave-uniform -> SGPRs
// (v_fma_f32 takes one scalar source: the query). Lanes stream 4 targets per
// superstep via ds_read_b128, register double-buffered. Inner math per
// (query, target): 3 scalar v_fma_f32 + 0.5 v_min3_f32.
//
// R5 post-mortem: 52us invariant across FOUR schedules (2 vs 4 waves/SIMD,
// AGPR fix, ping-pong, stagger+b128; bank conflicts 0/2.1M/6.3M all null).
// The only shared element was the v_pk_fma_f32 core. Cycle model: pk at
// full rate predicts ~31us total (wrong); pk fp32 at HALF rate (8cy/wave64,
// packing saves issue slots but not math) predicts 44.4+5+2 = 51.5us -> fits
// exactly. gfx950 ISA ref lists no packed-fp32 ops; 157.3 TF spec = scalar
// v_fma_f32 at 1 FMA/lane/cy. R6 therefore tests scalar v_fma_f32 (inline
// asm so SLP can't re-form pk): 224 instrs / 448 exec-cy per 16q x 4t quad,
// half the half-rate-pk cost. If still 52us -> pivot to MFMA formulation.

#define NPTS 16384
constexpr int NQ   = 16;            // queries per wave
constexpr int NW   = 8;             // waves per block (4 q-groups x 2 t-halves)
constexpr int QPB  = 64;            // queries per block
constexpr int SEGH = 2048;          // targets per half-segment
constexpr int NSS  = 8;             // supersteps per half-segment (256 targets)
constexpr int HALF = NPTS / 2;      // 8192 targets per half
constexpr int NBLK = NPTS / QPB;    // 256 blocks per direction

typedef float v4f __attribute__((ext_vector_type(4)));

// 4 targets (v4f regs) vs all NQ SGPR-resident queries:
// 192 v_fma_f32 + 32 v_min3_f32 per lane.
#define CD_Q4(tx4, ty4, tz4, tw4)                                             \
    _Pragma("unroll")                                                         \
    for (int i = 0; i < NQ; ++i) {                                            \
        float d0, d1, d2, d3, t23, mi;                                        \
        asm("v_fma_f32 %0, %1, %2, %3"                                        \
            : "=v"(d0) : "s"(qz[i]), "v"(tz4.x), "v"(tw4.x));                 \
        asm("v_fma_f32 %0, %1, %2, %3"                                        \
            : "=v"(d1) : "s"(qz[i]), "v"(tz4.y), "v"(tw4.y));                 \
        asm("v_fma_f32 %0, %1, %2, %3"                                        \
            : "=v"(d2) : "s"(qz[i]), "v"(tz4.z), "v"(tw4.z));                 \
        asm("v_fma_f32 %0, %1, %2, %3"                                        \
            : "=v"(d3) : "s"(qz[i]), "v"(tz4.w), "v"(tw4.w));                 \
        asm("v_fma_f32 %0, %1, %2, %0" : "+v"(d0) : "s"(qy[i]), "v"(ty4.x)); \
        asm("v_fma_f32 %0, %1, %2, %0" : "+v"(d1) : "s"(qy[i]), "v"(ty4.y)); \
        asm("v_fma_f32 %0, %1, %2, %0" : "+v"(d2) : "s"(qy[i]), "v"(ty4.z)); \
        asm("v_fma_f32 %0, %1, %2, %0" : "+v"(d3) : "s"(qy[i]), "v"(ty4.w)); \
        asm("v_fma_f32 %0, %1, %2, %0" : "+v"(d0) : "s"(qx[i]), "v"(tx4.x)); \
        asm("v_fma_f32 %0, %1, %2, %0" : "+v"(d1) : "s"(qx[i]), "v"(tx4.y)); \
        asm("v_fma_f32 %0, %1, %2, %0" : "+v"(d2) : "s"(qx[i]), "v"(tx4.z)); \
        asm("v_fma_f32 %0, %1, %2, %0" : "+v"(d3) : "s"(qx[i]), "v"(tx4.w)); \
        asm("v_min3_f32 %0, %1, %2, %3"                                       \
            : "=v"(t23) : "v"(d2), "v"(d3), "v"(m[i]));                       \
        asm("v_min3_f32 %0, %1, %2, %3"                                       \
            : "=v"(mi) : "v"(d0), "v"(d1), "v"(t23));                         \
        m[i] = mi;                                                            \
    }

__global__ __launch_bounds__(512, 4) void cd_main(const float* __restrict__ gt,
                                                  const float* __restrict__ gen,
                                                  float* __restrict__ part) {
    const int dir = blockIdx.y;                    // 0: gt->gen, 1: gen->gt
    const float* __restrict__ Q = dir ? gen : gt;
    const float* __restrict__ T = dir ? gt : gen;

    __shared__ float TX[2 * SEGH], TY[2 * SEGH], TZ[2 * SEGH], TW[2 * SEGH];
    __shared__ float wm[NW][NQ];

    const int lane = threadIdx.x & 63;
    const int wave = __builtin_amdgcn_readfirstlane(threadIdx.x >> 6);
    const int qg   = wave & 3;                     // query group 0..3
    const int th   = wave >> 2;                    // target half 0..1

    // Wave-uniform query cache: scalar floats, kept in SGPRs by the "s"
    // asm constraints (hoisted by LICM; 48 SGPRs).
    const int qbase = blockIdx.x * QPB + qg * NQ;
    float qx[NQ], qy[NQ], qz[NQ];
    #pragma unroll
    for (int i = 0; i < NQ; ++i) {
        qx[i] = Q[3 * (qbase + i) + 0];
        qy[i] = Q[3 * (qbase + i) + 1];
        qz[i] = Q[3 * (qbase + i) + 2];
    }

    float m[NQ];
    #pragma unroll
    for (int i = 0; i < NQ; ++i) m[i] = FLT_MAX;

    const int base = th * SEGH + 4 * lane;         // this wave's LDS half

    for (int s = 0; s < HALF; s += SEGH) {
        // Stage + transform one 2048-pt segment per half into SoA LDS.
        #pragma unroll
        for (int k = 0; k < (2 * SEGH) / 512; ++k) {
            const int p = k * 512 + threadIdx.x;
            const int g = (p >> 11) * HALF + s + (p & (SEGH - 1));
            const float x = T[3 * g + 0];
            const float y = T[3 * g + 1];
            const float z = T[3 * g + 2];
            TX[p] = -2.0f * x;
            TY[p] = -2.0f * y;
            TZ[p] = -2.0f * z;
            TW[p] = fmaf(x, x, fmaf(y, y, z * z));
        }
        __syncthreads();

        // Superstep sweep, register double-buffered b128 quad loads.
        {
            v4f atx = *(const v4f*)&TX[base], aty = *(const v4f*)&TY[base];
            v4f atz = *(const v4f*)&TZ[base], atw = *(const v4f*)&TW[base];
            for (int j = 0; j < NSS; j += 2) {
                const int offB = base + (j + 1) * 256;
                v4f btx = *(const v4f*)&TX[offB], bty = *(const v4f*)&TY[offB];
                v4f btz = *(const v4f*)&TZ[offB], btw = *(const v4f*)&TW[offB];
                CD_Q4(atx, aty, atz, atw)
                const int offA = base + (((j + 2) & (NSS - 1)) * 256);
                atx = *(const v4f*)&TX[offA]; aty = *(const v4f*)&TY[offA];
                atz = *(const v4f*)&TZ[offA]; atw = *(const v4f*)&TW[offA];
                CD_Q4(btx, bty, btz, btw)
            }
        }
        __syncthreads();
    }

    // Cross-lane min per query; lane 0 publishes per-wave mins to LDS.
    #pragma unroll
    for (int i = 0; i < NQ; ++i) {
        float v = m[i];
        #pragma unroll
        for (int off = 32; off > 0; off >>= 1)
            v = fminf(v, __shfl_down(v, off, 64));
        if (lane == 0) wm[wave][i] = v;
    }
    __syncthreads();

    // Wave 0: merge target halves, add |q|^2, sum the block's 64 queries.
    if (threadIdx.x < 64) {
        const int g = threadIdx.x >> 4;            // query group
        const int i = threadIdx.x & 15;            // query within group
        float v = fminf(wm[g][i], wm[g + 4][i]);
        const int q = blockIdx.x * QPB + g * NQ + i;
        const float x = Q[3 * q + 0];
        const float y = Q[3 * q + 1];
        const float z = Q[3 * q + 2];
        v += fmaf(x, x, fmaf(y, y, z * z));
        #pragma unroll
        for (int off = 32; off > 0; off >>= 1) v += __shfl_down(v, off, 64);
        if (threadIdx.x == 0) part[blockIdx.y * NBLK + blockIdx.x] = v;
    }
}

__global__ __launch_bounds__(512) void cd_reduce(const float* __restrict__ part,
                                                 float* __restrict__ out) {
    float v = part[threadIdx.x];                   // 512 partials, 512 threads
    #pragma unroll
    for (int off = 32; off > 0; off >>= 1) v += __shfl_down(v, off, 64);
    __shared__ float ws[8];
    const int lane = threadIdx.x & 63, w = threadIdx.x >> 6;
    if (lane == 0) ws[w] = v;
    __syncthreads();
    if (threadIdx.x == 0) {
        float s = 0.0f;
        #pragma unroll
        for (int i = 0; i < 8; ++i) s += ws[i];
        out[0] = s * (1.0f / (float)NPTS);
    }
}

extern "C" void kernel_launch(void* const* d_in, const int* in_sizes, int n_in,
                              void* d_out, int out_size, void* d_ws, size_t ws_size,
                              hipStream_t stream) {
    const float* gt  = (const float*)d_in[0];
    const float* gen = (const float*)d_in[1];
    float* part      = (float*)d_ws;               // 512 floats
    float* out       = (float*)d_out;

    dim3 grid(NBLK, 2);                            // 256 x 2 = 512 blocks
    cd_main<<<grid, 512, 0, stream>>>(gt, gen, part);
    cd_reduce<<<1, 512, 0, stream>>>(part, out);
}

// Round 7
// 85.832 us; speedup vs baseline: 1.3224x; 1.3224x over previous
//
#include <hip/hip_runtime.h>
#include <float.h>

// Chamfer distance, fp32, N=M=16384 — MFMA formulation (R7 pivot).
//
// R0-R6 established: the VALU formulation is pinned at ~52us across six
// schedules (occupancy x2, AGPR fix, SGPR queries, ping-pong, stagger, b128,
// scalar-vs-pk). Cost model: ~2.8 cyc/instr issued + ~33us invariant; at
// >=2 instrs per 2 (q,t) pairs the vector pipe can't go below ~50us.
//
// R7: d(q,t) = u.t + |t|^2 + |q|^2, u=-2q, is a K=4 dot product -> matrix
// cores. Precision: 2-level bf16 split with the FULL product expansion in
// one MFMA's K dim (K=14 of 32):
//   A k-slots: [uhx uhy uhz | ulx uly ulz | uhx uhy uhz | ulx uly ulz | 1 1]
//   B k-slots: [thx thy thz | thx thy thz | tlx tly tlz | tlx tly tlz | wh wl]
//   sum_k A*B = (uh+ul).(th+tl) + (wh+wl)  — no dropped cross-term; error
//   only from the ~2^-18-relative split representation (~1e-5 typical).
// One mfma_f32_16x16x32_bf16 = 256 pairs in ~5 cyc vs 512 VALU-cyc today.
// Per tile per lane: 1 ds_read_b128 (B-frag) + 2 MFMA (2 query-frags) +
// 8 v_min_f32. Min accumulates in C-layout; one cross-lane reduce at end.
//
// A-frag layout (16x32, lane l): row m = l&15, k = 8*(l>>4)+j. Lanes 32-63
// (k>=16) hold ZERO A -> their B reads may alias lanes 0-31 (finite garbage
// is annihilated). B-frag (32x16): col n = l&15, same k mapping. C/D: col =
// lane&15, row = (lane>>4)*4 + reg  [guide §3, m89-verified].

#define NPTS 16384
constexpr int QPB    = 128;              // queries per block
constexpr int QPW    = 32;               // queries per wave (2 A-frags)
constexpr int SEGT   = 1024;             // targets per half per round
constexpr int NROUND = (NPTS / 2) / SEGT;   // 8
constexpr int NTILE  = SEGT / 16;        // 64 tiles per half-segment
constexpr int NBLK   = NPTS / QPB;       // 128 blocks per direction

typedef float f32x4  __attribute__((ext_vector_type(4)));
typedef short bf16x8 __attribute__((ext_vector_type(8)));

__device__ inline ushort bf16rne(float f) {
    uint u = __float_as_uint(f);
    u += 0x7fff + ((u >> 16) & 1);      // round-to-nearest-even
    return (ushort)(u >> 16);
}
__device__ inline float bf2f(ushort h) { return __uint_as_float(((uint)h) << 16); }

__global__ __launch_bounds__(512) void cd_main(const float* __restrict__ gt,
                                               const float* __restrict__ gen,
                                               float* __restrict__ part) {
    const int dir = blockIdx.y;                    // 0: gt->gen, 1: gen->gt
    const float* __restrict__ Q = dir ? gen : gt;
    const float* __restrict__ T = dir ? gt : gen;

    // B-fragment store: [2 halves][NTILE tiles][32 lane-slots][8 bf16] = 64 KB
    __shared__ short FR[2 * NTILE * 32 * 8];
    __shared__ float wm[8][QPW];
    __shared__ float bsum[2];

    const int tid  = threadIdx.x;
    const int lane = tid & 63;
    const int wave = __builtin_amdgcn_readfirstlane(tid >> 6);
    const int qg   = wave & 3;                     // query group 0..3
    const int th   = wave >> 2;                    // target half 0..1

    // ---- Build 2 A-frags per wave (once). row = lane&15, kb = lane>>4. ----
    const int row = lane & 15, kb = lane >> 4;
    const int qbase = blockIdx.x * QPB + qg * QPW;
    bf16x8 afrag[2];
    #pragma unroll
    for (int f = 0; f < 2; ++f) {
        const int q = qbase + f * 16 + row;
        const float x = Q[3 * q + 0], y = Q[3 * q + 1], z = Q[3 * q + 2];
        const float ux = -2.f * x, uy = -2.f * y, uz = -2.f * z;
        const ushort uhx = bf16rne(ux), uhy = bf16rne(uy), uhz = bf16rne(uz);
        const ushort ulx = bf16rne(ux - bf2f(uhx));
        const ushort uly = bf16rne(uy - bf2f(uhy));
        const ushort ulz = bf16rne(uz - bf2f(uhz));
        bf16x8 a = (bf16x8)((short)0);             // lanes 32-63: zero (k>=16)
        if (kb == 0)
            a = (bf16x8){(short)uhx, (short)uhy, (short)uhz, (short)ulx,
                         (short)uly, (short)ulz, (short)uhx, (short)uhy};
        else if (kb == 1)
            a = (bf16x8){(short)uhz, (short)ulx, (short)uly, (short)ulz,
                         (short)0x3f80, (short)0x3f80, (short)0, (short)0};
        afrag[f] = a;
    }

    f32x4 mm0 = (f32x4)(FLT_MAX), mm1 = (f32x4)(FLT_MAX);
    const f32x4 zc = (f32x4)(0.f);

    // Prefetch round 0's raw targets (4 per thread covers both halves).
    float px[4], py[4], pz[4];
    #pragma unroll
    for (int k = 0; k < 4; ++k) {
        const int idx = k * 512 + tid;             // 0..2047
        const int g = (idx >> 10) * (NPTS / 2) + (idx & (SEGT - 1));
        px[k] = T[3 * g + 0]; py[k] = T[3 * g + 1]; pz[k] = T[3 * g + 2];
    }

    for (int r = 0; r < NROUND; ++r) {
        __syncthreads();                           // FR free (prev sweep done)

        // Split + pack prefetched targets into B-frag layout in LDS.
        #pragma unroll
        for (int k = 0; k < 4; ++k) {
            const int idx  = k * 512 + tid;
            const int half = idx >> 10, tloc = idx & (SEGT - 1);
            const float x = px[k], y = py[k], z = pz[k];
            const ushort thx = bf16rne(x), thy = bf16rne(y), thz = bf16rne(z);
            const ushort tlx = bf16rne(x - bf2f(thx));
            const ushort tly = bf16rne(y - bf2f(thy));
            const ushort tlz = bf16rne(z - bf2f(thz));
            const float w = fmaf(x, x, fmaf(y, y, z * z));
            const ushort wh = bf16rne(w), wl = bf16rne(w - bf2f(wh));
            const int tile = tloc >> 4, col = tloc & 15;
            short* base = &FR[half * (NTILE * 256) + tile * 256];
            *(bf16x8*)(base + col * 8) =
                (bf16x8){(short)thx, (short)thy, (short)thz, (short)thx,
                         (short)thy, (short)thz, (short)tlx, (short)tly};
            *(bf16x8*)(base + 128 + col * 8) =
                (bf16x8){(short)tlz, (short)tlx, (short)tly, (short)tlz,
                         (short)wh, (short)wl, (short)0, (short)0};
        }
        __syncthreads();                           // FR ready

        // Issue next round's raw loads now; latency hides under the sweep.
        if (r + 1 < NROUND) {
            #pragma unroll
            for (int k = 0; k < 4; ++k) {
                const int idx = k * 512 + tid;
                const int g = (idx >> 10) * (NPTS / 2) + (r + 1) * SEGT
                            + (idx & (SEGT - 1));
                px[k] = T[3 * g + 0]; py[k] = T[3 * g + 1]; pz[k] = T[3 * g + 2];
            }
        }

        // Sweep this wave's half: 64 tiles x (1 ds_read_b128 + 2 MFMA + 8 min).
        const short* rb = &FR[th * (NTILE * 256) + (lane & 31) * 8];
        #pragma unroll 4
        for (int t = 0; t < NTILE; ++t) {
            const bf16x8 b = *(const bf16x8*)(rb + t * 256);
            const f32x4 d0 = __builtin_amdgcn_mfma_f32_16x16x32_bf16(afrag[0], b, zc, 0, 0, 0);
            const f32x4 d1 = __builtin_amdgcn_mfma_f32_16x16x32_bf16(afrag[1], b, zc, 0, 0, 0);
            #pragma unroll
            for (int i = 0; i < 4; ++i) {
                mm0[i] = fminf(mm0[i], d0[i]);
                mm1[i] = fminf(mm1[i], d1[i]);
            }
        }
    }

    // Cross-lane min over the 16 target-cols (lanes within each 16-group).
    #pragma unroll
    for (int i = 0; i < 4; ++i) {
        float v0 = mm0[i], v1 = mm1[i];
        #pragma unroll
        for (int off = 1; off <= 8; off <<= 1) {
            v0 = fminf(v0, __shfl_xor(v0, off, 64));
            v1 = fminf(v1, __shfl_xor(v1, off, 64));
        }
        if ((lane & 15) == 0) {
            wm[wave][(lane >> 4) * 4 + i]      = v0;   // rows 4g+i, frag 0
            wm[wave][16 + (lane >> 4) * 4 + i] = v1;   // rows 16+4g+i, frag 1
        }
    }
    __syncthreads();

    // Merge target halves, add |q|^2, sum the block's 128 queries.
    if (tid < 128) {
        const int g2 = tid >> 5;                   // query group 0..3
        const int qr = tid & 31;                   // query within group
        float v = fminf(wm[g2][qr], wm[g2 + 4][qr]);
        const int q = blockIdx.x * QPB + g2 * QPW + qr;
        const float x = Q[3 * q + 0], y = Q[3 * q + 1], z = Q[3 * q + 2];
        v += fmaf(x, x, fmaf(y, y, z * z));
        #pragma unroll
        for (int off = 32; off > 0; off >>= 1) v += __shfl_down(v, off, 64);
        if ((tid & 63) == 0) bsum[tid >> 6] = v;
    }
    __syncthreads();
    if (tid == 0) part[blockIdx.y * NBLK + blockIdx.x] = bsum[0] + bsum[1];
}

__global__ __launch_bounds__(256) void cd_reduce(const float* __restrict__ part,
                                                 float* __restrict__ out) {
    float v = part[threadIdx.x];                   // 256 partials
    #pragma unroll
    for (int off = 32; off > 0; off >>= 1) v += __shfl_down(v, off, 64);
    __shared__ float ws[4];
    const int lane = threadIdx.x & 63, w = threadIdx.x >> 6;
    if (lane == 0) ws[w] = v;
    __syncthreads();
    if (threadIdx.x == 0)
        out[0] = (ws[0] + ws[1] + ws[2] + ws[3]) * (1.0f / (float)NPTS);
}

extern "C" void kernel_launch(void* const* d_in, const int* in_sizes, int n_in,
                              void* d_out, int out_size, void* d_ws, size_t ws_size,
                              hipStream_t stream) {
    const float* gt  = (const float*)d_in[0];
    const float* gen = (const float*)d_in[1];
    float* part      = (float*)d_ws;               // 256 floats
    float* out       = (float*)d_out;

    dim3 grid(NBLK, 2);                            // 128 x 2 = 256 blocks
    cd_main<<<grid, 512, 0, stream>>>(gt, gen, part);
    cd_reduce<<<1, 256, 0, stream>>>(part, out);
}

// Round 8
// 81.728 us; speedup vs baseline: 1.3888x; 1.0502x over previous
//
#include <hip/hip_runtime.h>
#include <float.h>

// Chamfer distance, fp32, N=M=16384 — MFMA 32x32 + precomputed B-frags (R8).
//
// d(q,t) = u.t + |t|^2 + |q|^2, u=-2q, K=4 dot -> matrix cores via 2-level
// bf16 split, full product expansion packed in K=14 of 16 (verified exact in
// R7: absmax 0.0):
//   k:      0..2     3..5     6..7+8   9..11    12 13
//   A:    uh(xyz)  ul(xyz)  uh(xyz)  ul(xyz)    1  1
//   B:    th(xyz)  th(xyz)  tl(xyz)  tl(xyz)   wh wl
//
// R7 post-mortem: cd_main 40us, MfmaUtil 33 / VALUBusy 38 / occ 18 -> no
// pipe saturated; waste = (a) 16x16 MFMA 2.6x less cycle-efficient than
// 32x32, (b) 256 blocks each re-split the same 16384 targets (~30 VALU
// ops/target) into LDS, (c) LDS+2 barriers/round for data that is only
// 512KB/set (L2-resident). R8: cd_prep materializes both sets in B-frag
// layout once per iteration (1MB of the 256MB workspace); cd_main has no
// LDS staging/barriers: per wave 2 A-frags (64 queries), sweep 1/8 of
// targets via coalesced 1KB global loads (L2 hit), 1 mfma_f32_32x32x16_bf16
// + 16 v_min per A-frag per 32 targets. Grid 512 -> 2 blk/CU, 4 waves/SIMD.
//
// Layouts (guide §3, m74/m101-verified for 32x32):
//   A (32r x 16k): row = lane&31, k = 8*(lane>>5)+j
//   B (16k x 32c): col = lane&31, k = 8*(lane>>5)+j
//   D: col = lane&31, row = (reg&3) + 8*(reg>>2) + 4*(lane>>5)

#define NPTS 16384
constexpr int QPB   = 64;                 // queries per block (2 A-frags, shared by all waves)
constexpr int NBLK  = NPTS / QPB;         // 256 blocks per direction
constexpr int NFRAG = NPTS / 32;          // 512 B-frags per point set
constexpr int FPW   = NFRAG / 8;          // 64 frags swept per wave
constexpr int SET_SHORTS = NFRAG * 512;   // 262144 shorts = 512 KB per set

typedef float f32x16 __attribute__((ext_vector_type(16)));
typedef short bf16x8 __attribute__((ext_vector_type(8)));

__device__ inline ushort bf16rne(float f) {
    uint u = __float_as_uint(f);
    u += 0x7fff + ((u >> 16) & 1);        // round-to-nearest-even
    return (ushort)(u >> 16);
}
__device__ inline float bf2f(ushort h) { return __uint_as_float(((uint)h) << 16); }

// Split both point sets into B-fragment layout: bt[set][frag][lane][8 bf16].
// Thread block b<64 handles set 0 halves, etc. h = k-group (lane>>5).
__global__ __launch_bounds__(512) void cd_prep(const float* __restrict__ gt,
                                               const float* __restrict__ gen,
                                               short* __restrict__ bt) {
    const int t   = blockIdx.x * 512 + threadIdx.x;   // 0..65535
    const int set = t >> 15;                          // 0: gt, 1: gen
    const int rem = t & 32767;
    const int h   = rem >> 14;                        // k-group 0/1 (block-uniform)
    const int p   = rem & (NPTS - 1);                 // point index
    const float* __restrict__ src = set ? gen : gt;

    const float x = src[3 * p + 0], y = src[3 * p + 1], z = src[3 * p + 2];
    const ushort hx = bf16rne(x), hy = bf16rne(y), hz = bf16rne(z);
    const ushort lx = bf16rne(x - bf2f(hx));
    const ushort ly = bf16rne(y - bf2f(hy));
    const ushort lz = bf16rne(z - bf2f(hz));
    const float w = fmaf(x, x, fmaf(y, y, z * z));
    const ushort wh = bf16rne(w), wl = bf16rne(w - bf2f(wh));

    bf16x8 v;
    if (h == 0)
        v = (bf16x8){(short)hx, (short)hy, (short)hz, (short)hx,
                     (short)hy, (short)hz, (short)lx, (short)ly};
    else
        v = (bf16x8){(short)lz, (short)lx, (short)ly, (short)lz,
                     (short)wh, (short)wl, (short)0, (short)0};
    // frag = p>>5, col = p&31, lane = h*32+col
    *(bf16x8*)(bt + set * SET_SHORTS + (p >> 5) * 512 + (h * 32 + (p & 31)) * 8) = v;
}

__global__ __launch_bounds__(512, 4) void cd_main(const float* __restrict__ gt,
                                                  const float* __restrict__ gen,
                                                  const short* __restrict__ bt,
                                                  float* __restrict__ part) {
    const int dir = blockIdx.y;                    // 0: gt->gen, 1: gen->gt
    const float* __restrict__ Q = dir ? gen : gt;
    const short* __restrict__ BT = bt + (dir ? 0 : SET_SHORTS);  // opposite set

    __shared__ float wm[8][QPB];

    const int tid  = threadIdx.x;
    const int lane = tid & 63;
    const int wave = __builtin_amdgcn_readfirstlane(tid >> 6);

    // ---- 2 A-frags per wave (all waves share the same 64 queries). ----
    const int arow = lane & 31, kg = lane >> 5;
    const int qbase = blockIdx.x * QPB;
    bf16x8 a[2];
    #pragma unroll
    for (int f = 0; f < 2; ++f) {
        const int q = qbase + f * 32 + arow;
        const float x = Q[3 * q + 0], y = Q[3 * q + 1], z = Q[3 * q + 2];
        const float ux = -2.f * x, uy = -2.f * y, uz = -2.f * z;
        const ushort hx = bf16rne(ux), hy = bf16rne(uy), hz = bf16rne(uz);
        const ushort lx = bf16rne(ux - bf2f(hx));
        const ushort ly = bf16rne(uy - bf2f(hy));
        const ushort lz = bf16rne(uz - bf2f(hz));
        if (kg == 0)
            a[f] = (bf16x8){(short)hx, (short)hy, (short)hz, (short)lx,
                            (short)ly, (short)lz, (short)hx, (short)hy};
        else
            a[f] = (bf16x8){(short)hz, (short)lx, (short)ly, (short)lz,
                            (short)0x3f80, (short)0x3f80, (short)0, (short)0};
    }

    f32x16 mm0 = (f32x16)(FLT_MAX), mm1 = (f32x16)(FLT_MAX);
    const f32x16 zc = (f32x16)(0.f);

    // ---- Sweep this wave's 64 B-frags straight from L2 (no LDS). ----
    const short* rb = BT + (wave * FPW) * 512 + lane * 8;
    #pragma unroll 2
    for (int f2 = 0; f2 < FPW; ++f2) {
        const bf16x8 b = *(const bf16x8*)(rb + f2 * 512);   // 1KB/wave, coalesced
        const f32x16 d0 = __builtin_amdgcn_mfma_f32_32x32x16_bf16(a[0], b, zc, 0, 0, 0);
        const f32x16 d1 = __builtin_amdgcn_mfma_f32_32x32x16_bf16(a[1], b, zc, 0, 0, 0);
        #pragma unroll
        for (int i = 0; i < 16; ++i) {
            mm0[i] = fminf(mm0[i], d0[i]);
            mm1[i] = fminf(mm1[i], d1[i]);
        }
    }

    // ---- Cross-lane min over the 32 target-cols of each D row. ----
    #pragma unroll
    for (int i = 0; i < 16; ++i) {
        float v0 = mm0[i], v1 = mm1[i];
        #pragma unroll
        for (int off = 1; off <= 16; off <<= 1) {
            v0 = fminf(v0, __shfl_xor(v0, off, 64));
            v1 = fminf(v1, __shfl_xor(v1, off, 64));
        }
        const int row = (i & 3) + 8 * (i >> 2) + 4 * kg;
        if ((lane & 31) == 0) {
            wm[wave][row]      = v0;               // frag 0: queries qbase+row
            wm[wave][32 + row] = v1;               // frag 1: queries qbase+32+row
        }
    }
    __syncthreads();

    // ---- Merge the 8 wave-slices, add |q|^2, sum the block's 64 queries. ----
    if (tid < QPB) {
        float v = wm[0][tid];
        #pragma unroll
        for (int w = 1; w < 8; ++w) v = fminf(v, wm[w][tid]);
        const int q = qbase + tid;
        const float x = Q[3 * q + 0], y = Q[3 * q + 1], z = Q[3 * q + 2];
        v += fmaf(x, x, fmaf(y, y, z * z));
        #pragma unroll
        for (int off = 32; off > 0; off >>= 1) v += __shfl_down(v, off, 64);
        if (tid == 0) part[blockIdx.y * NBLK + blockIdx.x] = v;
    }
}

__global__ __launch_bounds__(512) void cd_reduce(const float* __restrict__ part,
                                                 float* __restrict__ out) {
    float v = part[threadIdx.x];                   // 512 partials, 512 threads
    #pragma unroll
    for (int off = 32; off > 0; off >>= 1) v += __shfl_down(v, off, 64);
    __shared__ float ws[8];
    const int lane = threadIdx.x & 63, w = threadIdx.x >> 6;
    if (lane == 0) ws[w] = v;
    __syncthreads();
    if (threadIdx.x == 0) {
        float s = 0.0f;
        #pragma unroll
        for (int i = 0; i < 8; ++i) s += ws[i];
        out[0] = s * (1.0f / (float)NPTS);
    }
}

extern "C" void kernel_launch(void* const* d_in, const int* in_sizes, int n_in,
                              void* d_out, int out_size, void* d_ws, size_t ws_size,
                              hipStream_t stream) {
    const float* gt  = (const float*)d_in[0];
    const float* gen = (const float*)d_in[1];
    short* bt        = (short*)d_ws;                       // 2 x 512 KB B-frags
    float* part      = (float*)((short*)d_ws + 2 * SET_SHORTS);  // 512 floats
    float* out       = (float*)d_out;

    cd_prep<<<128, 512, 0, stream>>>(gt, gen, bt);
    dim3 grid(NBLK, 2);                                    // 256 x 2 = 512 blocks
    cd_main<<<grid, 512, 0, stream>>>(gt, gen, bt, part);
    cd_reduce<<<1, 512, 0, stream>>>(part, out);
}